// Round 1
// baseline (193.057 us; speedup 1.0000x reference)
//
// Round 12: 3 kernels -> 2.
//  A (k_zfused): proj fused directly into z (per (b,e,mq)-block recompute from x/w_attn,
//     slow-path style but 512 thr, 4 m-slices), zbar via per-slice PARTIAL slots (no
//     atomics, no zero-init kernel), misc (x_hat/edge_mask/mask) in spare blocks.
//  B (k_epi): round-9 epilogue core, + sums 4 zbar partials, + recomputes wpc/c1
//     per-block (w_ctx is 16KB, L2-hot).
// ws usage: zs bf16 [0, 327680 floats) + zbar partials 4*5120 floats = 1.4 MB total.
#include <hip/hip_runtime.h>
#include <hip/hip_bf16.h>

#define NB 8
#define NMAXN 128
#define PEH 64
#define NE 5
#define DSZ 64
#define NFEAT 8
#define TOTALN 1024         // NB*NMAXN
#define PCOLS 1280          // 4*E*PE

// out layout (FLOAT32 offsets): e_hat, x_hat, edge_mask, mask
#define OUT_XHAT (NB*NMAXN*NMAXN*NE)              // 655360
#define OUT_EM   (OUT_XHAT + TOTALN*NFEAT)        // 663552
#define OUT_MASK (OUT_EM + NB*NMAXN*NMAXN)        // 794624

// ws layout (float offsets): zs bf16 at 0 (327680 float-units), then 4 zbar partials
#define OFF_ZBAR 327680
#define ZBAR_STRIDE 5120    // NB*NE*NMAXN per partial

// ---------------- Kernel A: fused proj+z (blocks 0..159) + misc (160..192), 512 thr
// z block (be = blk>>2, mq = blk&3): computes z[b,e, n=0..127, m=mq*32..mq*32+31]
//   = sum_pe scale*k1[n,pe]*q1[m,pe] + scale*fac*k2[n,pe]*q2[m,pe]
// with k1/q1/k2/q2 projected on the fly from x[b] (LDS-staged) and w_attn (L2-hot).
__global__ __launch_bounds__(512)
void k_zfused(const float* __restrict__ x, const float* __restrict__ qv,
              const float* __restrict__ w_attn, const float* __restrict__ b_attn,
              const float* __restrict__ w_node, const float* __restrict__ b_node,
              float* __restrict__ ws, float* __restrict__ out)
{
    int blk = blockIdx.x, t = threadIdx.x;
    if (blk >= 160) {                      // ---------- misc blocks
        int b2 = blk - 160;
        if (b2 < 16) {                     // x_hat: 8192 outputs, 1/thread
            int g = b2 * 512 + t;
            int row = g >> 3, f = g & 7;
            const float* xr = x + row * PEH;
            float acc = b_node[f];
            #pragma unroll 8
            for (int k = 0; k < PEH; k++) acc = fmaf(xr[k], w_node[k * NFEAT + f], acc);
            out[OUT_XHAT + g] = acc;
        } else if (b2 < 32) {              // edge_mask: 131072 elems
            int base = (b2 - 16) * 8192;
            for (int g = base + t; g < base + 8192; g += 512) {
                int n = (g >> 7) & 127, m = g & 127;
                out[OUT_EM + g] = (n == m) ? 0.0f : 1.0f;
            }
        } else {                           // mask: 1024 elems
            for (int g = t; g < 1024; g += 512) out[OUT_MASK + g] = 1.0f;
        }
        return;
    }

    // ---------- z block
    __shared__ alignas(16) float sm[8320 + 2304];
    float* xsm = sm;          // [128][65]  (aliased with smA; x restaged per pass)
    float* smA = sm;          // [64 pe][128 n], scaled
    float* smQ = sm + 8320;   // [64 pe][36] (32 m + pad)
    float* zp  = sm + 8320;   // aliases smQ after passes: [128 n][16]

    int be = blk >> 2, mq = blk & 3;
    int b = be / 5, e = be - 5 * b;
    float ang = 6.2831853071795864f * qv[b];
    float fac = (2.0f - cosf(ang)) / sinf(ang);
    const float scale = 0.05590169943749474f;   // 1/sqrt(320)
    float sfac = scale * fac;

    int kn = t >> 2, kkb = (t & 3) * 16;        // K-proj: row n, 16-col slab
    int qm = t & 31, qkb = (t >> 5) * 4;        // Q-proj: m-local, 4-col slab
    int qrow = mq * 32 + qm;

    int tx = t & 15, ty = t >> 4;
    int m0 = 2 * tx, n0 = 4 * ty;               // thread tile: 4n x 2m
    float acc[4][2] = {};

    for (int pass = 0; pass < 2; pass++) {
        __syncthreads();                        // prior-pass z-accum done with smA/smQ
        // stage x[b] (128x64) into xsm, stride 65
        for (int i = t; i < 128 * 16; i += 512) {
            int n = i >> 4, dd = (i & 15) * 4;
            float4 xv = *(const float4*)&x[(b * NMAXN + n) * PEH + dd];
            float* dst = &xsm[n * 65 + dd];
            dst[0] = xv.x; dst[1] = xv.y; dst[2] = xv.z; dst[3] = xv.w;
        }
        __syncthreads();
        int cK = (pass ? 640 : 0)   + e * 64 + kkb;
        int cQ = (pass ? 960 : 320) + e * 64 + qkb;
        float rk[16], rq[4];
        #pragma unroll
        for (int j = 0; j < 16; j++) rk[j] = b_attn[cK + j];
        #pragma unroll
        for (int j = 0; j < 4; j++)  rq[j] = b_attn[cQ + j];
        #pragma unroll 4
        for (int d = 0; d < 64; d++) {
            const float* wr = w_attn + d * PCOLS;
            float xk = xsm[kn * 65 + d];
            float xq = xsm[qrow * 65 + d];
            #pragma unroll
            for (int j4 = 0; j4 < 4; j4++) {
                float4 w4 = *(const float4*)&wr[cK + 4 * j4];
                rk[4*j4+0] = fmaf(xk, w4.x, rk[4*j4+0]);
                rk[4*j4+1] = fmaf(xk, w4.y, rk[4*j4+1]);
                rk[4*j4+2] = fmaf(xk, w4.z, rk[4*j4+2]);
                rk[4*j4+3] = fmaf(xk, w4.w, rk[4*j4+3]);
            }
            float4 wq = *(const float4*)&wr[cQ];
            rq[0] = fmaf(xq, wq.x, rq[0]);
            rq[1] = fmaf(xq, wq.y, rq[1]);
            rq[2] = fmaf(xq, wq.z, rq[2]);
            rq[3] = fmaf(xq, wq.w, rq[3]);
        }
        __syncthreads();                        // all done reading xsm
        float sc = pass ? sfac : scale;
        #pragma unroll
        for (int j = 0; j < 16; j++) smA[(kkb + j) * 128 + kn] = sc * rk[j];
        #pragma unroll
        for (int j = 0; j < 4; j++)  smQ[(qkb + j) * 36 + qm] = rq[j];
        __syncthreads();
        for (int k = 0; k < 64; k++) {
            float4 a4 = *(const float4*)&smA[k * 128 + n0];
            float2 q2 = *(const float2*)&smQ[k * 36 + m0];
            float ar[4] = {a4.x, a4.y, a4.z, a4.w};
            #pragma unroll
            for (int r = 0; r < 4; r++) {
                acc[r][0] = fmaf(ar[r], q2.x, acc[r][0]);
                acc[r][1] = fmaf(ar[r], q2.y, acc[r][1]);
            }
        }
    }
    __syncthreads();                            // z-accum done before zp (smQ alias) reuse

    // store zs bf16 [b][m][e][n] + zbar partial (diagonal excluded), no atomics
    __hip_bfloat16* zsb = (__hip_bfloat16*)ws;
    float psum[4] = {0.f, 0.f, 0.f, 0.f};
    #pragma unroll
    for (int c = 0; c < 2; c++) {
        int mg = mq * 32 + m0 + c;
        union { ushort4 u; __hip_bfloat16 h[4]; } pk;
        #pragma unroll
        for (int r = 0; r < 4; r++) {
            pk.h[r] = __float2bfloat16(acc[r][c]);
            if (mg != n0 + r) psum[r] += acc[r][c];
        }
        *(ushort4*)&zsb[((b * NMAXN + mg) * NE + e) * NMAXN + n0] = pk.u;
    }
    #pragma unroll
    for (int r = 0; r < 4; r++) zp[(n0 + r) * 16 + tx] = psum[r];
    __syncthreads();
    if (t < 128) {
        float s = 0.f;
        #pragma unroll
        for (int xx = 0; xx < 16; xx++) s += zp[t * 16 + xx];
        ws[OFF_ZBAR + mq * ZBAR_STRIDE + (b * NE + e) * NMAXN + t] = s;
    }
}

// gelu tanh-approx: x * sigmoid(2u), u=sqrt(2/pi)(x+0.044715x^3)
__device__ __forceinline__ float gelu_fast(float x) {
    float x2 = x * x;
    float w  = -1.5957691216057308f * x * fmaf(0.044715f, x2, 1.0f);   // -2u
    float ew = __expf(w);
    return x * __builtin_amdgcn_rcpf(1.0f + ew);
}

// ---------------- Kernel B: epilogue. grid 512 = (b x 64 m-pairs), 640 thr (t=e*128+n),
// 2 m's per thread; consts (wpc,c1) recomputed per block; zbar = sum of 4 partials.
__global__ void k_epi(const float* __restrict__ ws,
                      const float* __restrict__ w_phi, const float* __restrict__ b_phi,
                      const float* __restrict__ w_ctx,
                      const float* __restrict__ w_self, const float* __restrict__ b_self,
                      const float* __restrict__ w_out, const float* __restrict__ b_out,
                      float* __restrict__ out)
{
    __shared__ alignas(16) float4 cwi[64];   // (w_self, wpc, c1, w_out)
    int t = threadIdx.x;
    int b = blockIdx.x >> 6, mp = blockIdx.x & 63;
    int m0 = 2 * mp;
    if (t < 64) {
        float wpv = 0.f, bpv = 0.f;
        #pragma unroll 8
        for (int i = 0; i < 64; i++) {
            float wc = w_ctx[i * 64 + t];          // coalesced: lanes t=0..63
            wpv = fmaf(w_phi[i], wc, wpv);
            bpv = fmaf(b_phi[i], wc, bpv);
        }
        cwi[t] = make_float4(w_self[t], wpv, b_self[t] + bpv, w_out[t]);
    }
    const float* zb = ws + OFF_ZBAR + b * 640 + t;  // [b][e][n], t=(e,n)
    float zbv = (zb[0] + zb[ZBAR_STRIDE] + zb[2 * ZBAR_STRIDE] + zb[3 * ZBAR_STRIDE])
                * (1.0f / 127.0f);
    __syncthreads();

    const __hip_bfloat16* zsb = (const __hip_bfloat16*)ws;
    int e = t >> 7, n = t & 127;
    float zv0 = __bfloat162float(zsb[(b * NMAXN + m0) * 640 + t]);      // [b][m][e][n]
    float zv1 = __bfloat162float(zsb[(b * NMAXN + m0 + 1) * 640 + t]);
    float bo = b_out[0];
    float a0 = bo, a1 = bo;
    #pragma unroll 8
    for (int d = 0; d < 64; d++) {
        float4 c = cwi[d];
        float zc = fmaf(zbv, c.y, c.z);
        a0 = fmaf(gelu_fast(fmaf(zv0, c.x, zc)), c.w, a0);
        a1 = fmaf(gelu_fast(fmaf(zv1, c.x, zc)), c.w, a1);
    }
    int oo = n * NE + e;
    out[(b * NMAXN + m0) * 640 + oo]     = a0;
    out[(b * NMAXN + m0 + 1) * 640 + oo] = a1;
}

extern "C" void kernel_launch(void* const* d_in, const int* in_sizes, int n_in,
                              void* d_out, int out_size, void* d_ws, size_t ws_size,
                              hipStream_t stream)
{
    const float* x      = (const float*)d_in[0];
    // d_in[1] = batch (int32) — full sorted graphs, unused
    const float* q      = (const float*)d_in[2];
    const float* w_attn = (const float*)d_in[3];
    const float* b_attn = (const float*)d_in[4];
    const float* w_node = (const float*)d_in[5];
    const float* b_node = (const float*)d_in[6];
    const float* w_phi  = (const float*)d_in[7];
    const float* b_phi  = (const float*)d_in[8];
    const float* w_ctx  = (const float*)d_in[9];
    const float* w_self = (const float*)d_in[10];
    const float* b_self = (const float*)d_in[11];
    const float* w_out  = (const float*)d_in[12];
    const float* b_out  = (const float*)d_in[13];
    float* ws  = (float*)d_ws;
    float* out = (float*)d_out;

    k_zfused<<<193, 512, 0, stream>>>(x, q, w_attn, b_attn, w_node, b_node, ws, out);
    k_epi<<<512, 640, 0, stream>>>(ws, w_phi, b_phi, w_ctx, w_self, b_self, w_out, b_out, out);
}

// Round 3
// 125.728 us; speedup vs baseline: 1.5355x; 1.5355x over previous
//
// Round 14: identical to round 13 (bench infra failed: "container failed twice";
// static audit found no OOB/deadlock/LDS issue — resubmitting unchanged).
//  K1 (k_front): proj as tiled GEMM (64rows x 128cols per block, X in LDS, W streamed
//     from L2 once per col-tile instead of 256x) + misc (x_hat/edge_mask/mask).
//     L2 traffic for proj: 1.3 GB -> ~5 MB.
//  K2 (k_zepi): z + epilogue fused. Block = (b,e,n-slice of 32) computes z[32n x 128m]
//     from precomputed proj (LDS-staged), zbar block-locally (all m local -> no atomics,
//     no zero-init, no bf16 zs round-trip), then the gelu epilogue on f32 z in registers.
// ws: proj only (1,310,720 floats = 5.24 MB).
#include <hip/hip_runtime.h>
#include <hip/hip_bf16.h>

#define NB 8
#define NMAXN 128
#define PEH 64
#define NE 5
#define DSZ 64
#define NFEAT 8
#define TOTALN 1024         // NB*NMAXN
#define PCOLS 1280          // 4*E*PE

// out layout (FLOAT32 offsets): e_hat, x_hat, edge_mask, mask
#define OUT_XHAT (NB*NMAXN*NMAXN*NE)              // 655360
#define OUT_EM   (OUT_XHAT + TOTALN*NFEAT)        // 663552
#define OUT_MASK (OUT_EM + NB*NMAXN*NMAXN)        // 794624

// ---------------- K1: proj tiled GEMM (blocks 0..159) + misc (160..208), 256 thr
// proj block: rows r0..r0+63 (one 64-row slab of x), cols c0..c0+127.
// thread tile: 8 rows x 4 cols. X staged in LDS transposed [k][row].
__global__ __launch_bounds__(256)
void k_front(const float* __restrict__ x,
             const float* __restrict__ w_attn, const float* __restrict__ b_attn,
             const float* __restrict__ w_node, const float* __restrict__ b_node,
             float* __restrict__ ws, float* __restrict__ out)
{
    int blk = blockIdx.x, t = threadIdx.x;
    if (blk < 160) {                       // ---------- proj GEMM
        __shared__ alignas(16) float xs[64 * 68];   // [k][row], pad 68
        int rt = blk / 10, ct = blk - 10 * rt;
        int r0 = rt * 64, c0 = ct * 128;
        #pragma unroll
        for (int it = 0; it < 4; it++) {
            int g = it * 256 + t;          // 0..1023
            int row = g >> 4, kk = (g & 15) * 4;
            float4 v = *(const float4*)&x[(r0 + row) * PEH + kk];
            xs[(kk + 0) * 68 + row] = v.x;
            xs[(kk + 1) * 68 + row] = v.y;
            xs[(kk + 2) * 68 + row] = v.z;
            xs[(kk + 3) * 68 + row] = v.w;
        }
        __syncthreads();
        int tx = t & 31, ty = t >> 5;
        int cc = c0 + 4 * tx, rr = 8 * ty;
        float4 bb = *(const float4*)&b_attn[cc];
        float acc[8][4];
        #pragma unroll
        for (int r = 0; r < 8; r++) {
            acc[r][0] = bb.x; acc[r][1] = bb.y; acc[r][2] = bb.z; acc[r][3] = bb.w;
        }
        const float* wp = w_attn + cc;
        #pragma unroll 8
        for (int k = 0; k < 64; k++) {
            float4 w4 = *(const float4*)&wp[k * PCOLS];
            float4 xa = *(const float4*)&xs[k * 68 + rr];
            float4 xb = *(const float4*)&xs[k * 68 + rr + 4];
            float xr[8] = {xa.x, xa.y, xa.z, xa.w, xb.x, xb.y, xb.z, xb.w};
            #pragma unroll
            for (int r = 0; r < 8; r++) {
                acc[r][0] = fmaf(xr[r], w4.x, acc[r][0]);
                acc[r][1] = fmaf(xr[r], w4.y, acc[r][1]);
                acc[r][2] = fmaf(xr[r], w4.z, acc[r][2]);
                acc[r][3] = fmaf(xr[r], w4.w, acc[r][3]);
            }
        }
        #pragma unroll
        for (int r = 0; r < 8; r++)
            *(float4*)&ws[(r0 + rr + r) * PCOLS + cc] =
                make_float4(acc[r][0], acc[r][1], acc[r][2], acc[r][3]);
        return;
    }
    int b2 = blk - 160;
    if (b2 < 32) {                         // ---------- x_hat: 8192 outputs
        int g = b2 * 256 + t;
        int row = g >> 3, f = g & 7;
        const float* xr = x + row * PEH;
        float acc = b_node[f];
        #pragma unroll 8
        for (int k = 0; k < PEH; k++) acc = fmaf(xr[k], w_node[k * NFEAT + f], acc);
        out[OUT_XHAT + g] = acc;
    } else if (b2 < 48) {                  // ---------- edge_mask
        int base = (b2 - 32) * 8192;
        for (int g = base + t; g < base + 8192; g += 256) {
            int n = (g >> 7) & 127, m = g & 127;
            out[OUT_EM + g] = (n == m) ? 0.0f : 1.0f;
        }
    } else {                               // ---------- mask
        for (int g = t; g < 1024; g += 256) out[OUT_MASK + g] = 1.0f;
    }
}

// gelu tanh-approx: x * sigmoid(2u), u=sqrt(2/pi)(x+0.044715x^3)
__device__ __forceinline__ float gelu_fast(float x) {
    float x2 = x * x;
    float w  = -1.5957691216057308f * x * fmaf(0.044715f, x2, 1.0f);   // -2u
    float ew = __expf(w);
    return x * __builtin_amdgcn_rcpf(1.0f + ew);
}

// ---------------- K2: z + epilogue fused. grid 160 = (b,e) x 4 n-slices, 512 thr.
// Block computes z[n-slice 32][all 128 m] (f32, registers), zbar locally, then gelu epi.
// thread tile: 2n x 4m (ty = t>>5 -> n, tx = t&31 -> m).
__global__ __launch_bounds__(512)
void k_zepi(const float* __restrict__ ws, const float* __restrict__ qv,
            const float* __restrict__ w_phi, const float* __restrict__ b_phi,
            const float* __restrict__ w_ctx,
            const float* __restrict__ w_self, const float* __restrict__ b_self,
            const float* __restrict__ w_out, const float* __restrict__ b_out,
            float* __restrict__ out)
{
    __shared__ alignas(16) float smA[64 * 36];    // [k][n-slice 32 + pad]
    __shared__ alignas(16) float smQ[64 * 132];   // [k][m 128 + pad]
    __shared__ alignas(16) float4 cwi[64];        // (w_self, wpc, c1, w_out)
    __shared__ float zp[32 * 33];                 // zbar partials [n][txgroup]
    __shared__ float zbs[32];

    int t = threadIdx.x, blk = blockIdx.x;
    int be = blk >> 2, nq = blk & 3;
    int b = be / 5, e = be - 5 * b;

    // per-block consts
    if (t < 64) {
        float wpv = 0.f, bpv = 0.f;
        #pragma unroll 8
        for (int i = 0; i < 64; i++) {
            float wc = w_ctx[i * 64 + t];
            wpv = fmaf(w_phi[i], wc, wpv);
            bpv = fmaf(b_phi[i], wc, bpv);
        }
        cwi[t] = make_float4(w_self[t], wpv, b_self[t] + bpv, w_out[t]);
    }
    float ang = 6.2831853071795864f * qv[b];
    float fac = (2.0f - cosf(ang)) / sinf(ang);
    const float scale = 0.05590169943749474f;   // 1/sqrt(320)

    int tx = t & 31, ty = t >> 5;
    float acc[2][4] = {};

    #pragma unroll
    for (int pass = 0; pass < 2; pass++) {
        __syncthreads();                        // smA/smQ free (and cwi visible later)
        int cK = (pass ? 640 : 0)   + e * 64;
        int cQ = (pass ? 960 : 320) + e * 64;
        float sc = pass ? (scale * fac) : scale;
        {   // K-side: 32 rows x 64 cols
            int r = t >> 4, kk = (t & 15) * 4;
            float4 v = *(const float4*)&ws[(b * NMAXN + nq * 32 + r) * PCOLS + cK + kk];
            smA[(kk + 0) * 36 + r] = sc * v.x;
            smA[(kk + 1) * 36 + r] = sc * v.y;
            smA[(kk + 2) * 36 + r] = sc * v.z;
            smA[(kk + 3) * 36 + r] = sc * v.w;
        }
        #pragma unroll
        for (int it = 0; it < 4; it++) {        // Q-side: 128 rows x 64 cols
            int g = it * 512 + t;
            int r = g >> 4, kk = (g & 15) * 4;
            float4 v = *(const float4*)&ws[(b * NMAXN + r) * PCOLS + cQ + kk];
            smQ[(kk + 0) * 132 + r] = v.x;
            smQ[(kk + 1) * 132 + r] = v.y;
            smQ[(kk + 2) * 132 + r] = v.z;
            smQ[(kk + 3) * 132 + r] = v.w;
        }
        __syncthreads();
        for (int k = 0; k < 64; k++) {
            float2 a2 = *(const float2*)&smA[k * 36 + 2 * ty];
            float4 q4 = *(const float4*)&smQ[k * 132 + 4 * tx];
            float qr[4] = {q4.x, q4.y, q4.z, q4.w};
            #pragma unroll
            for (int c = 0; c < 4; c++) {
                acc[0][c] = fmaf(a2.x, qr[c], acc[0][c]);
                acc[1][c] = fmaf(a2.y, qr[c], acc[1][c]);
            }
        }
    }

    // zbar partials (exclude diagonal), block-local reduce
    int ng0 = nq * 32 + 2 * ty;
    float psum0 = 0.f, psum1 = 0.f;
    #pragma unroll
    for (int c = 0; c < 4; c++) {
        int m = 4 * tx + c;
        if (m != ng0)     psum0 += acc[0][c];
        if (m != ng0 + 1) psum1 += acc[1][c];
    }
    zp[(2 * ty)     * 33 + tx] = psum0;
    zp[(2 * ty + 1) * 33 + tx] = psum1;
    __syncthreads();
    if (t < 32) {
        float s = 0.f;
        #pragma unroll
        for (int xx = 0; xx < 32; xx++) s += zp[t * 33 + xx];
        zbs[t] = s * (1.0f / 127.0f);
    }
    __syncthreads();
    float zbv0 = zbs[2 * ty], zbv1 = zbs[2 * ty + 1];

    // epilogue: 8 gelu chains over d=0..63
    float bo = b_out[0];
    float o0[4] = {bo, bo, bo, bo};
    float o1[4] = {bo, bo, bo, bo};
    #pragma unroll 8
    for (int d = 0; d < 64; d++) {
        float4 c = cwi[d];
        float zc0 = fmaf(zbv0, c.y, c.z);
        float zc1 = fmaf(zbv1, c.y, c.z);
        #pragma unroll
        for (int cc = 0; cc < 4; cc++) {
            o0[cc] = fmaf(gelu_fast(fmaf(acc[0][cc], c.x, zc0)), c.w, o0[cc]);
            o1[cc] = fmaf(gelu_fast(fmaf(acc[1][cc], c.x, zc1)), c.w, o1[cc]);
        }
    }
    // e_hat[b, m, n, e]
    #pragma unroll
    for (int cc = 0; cc < 4; cc++) {
        int m = 4 * tx + cc;
        out[(b * NMAXN + m) * 640 + ng0 * 5 + e]       = o0[cc];
        out[(b * NMAXN + m) * 640 + (ng0 + 1) * 5 + e] = o1[cc];
    }
}

extern "C" void kernel_launch(void* const* d_in, const int* in_sizes, int n_in,
                              void* d_out, int out_size, void* d_ws, size_t ws_size,
                              hipStream_t stream)
{
    const float* x      = (const float*)d_in[0];
    // d_in[1] = batch (int32) — full sorted graphs, unused
    const float* q      = (const float*)d_in[2];
    const float* w_attn = (const float*)d_in[3];
    const float* b_attn = (const float*)d_in[4];
    const float* w_node = (const float*)d_in[5];
    const float* b_node = (const float*)d_in[6];
    const float* w_phi  = (const float*)d_in[7];
    const float* b_phi  = (const float*)d_in[8];
    const float* w_ctx  = (const float*)d_in[9];
    const float* w_self = (const float*)d_in[10];
    const float* b_self = (const float*)d_in[11];
    const float* w_out  = (const float*)d_in[12];
    const float* b_out  = (const float*)d_in[13];
    float* ws  = (float*)d_ws;
    float* out = (float*)d_out;

    k_front<<<209, 256, 0, stream>>>(x, w_attn, b_attn, w_node, b_node, ws, out);
    k_zepi<<<160, 512, 0, stream>>>(ws, q, w_phi, b_phi, w_ctx,
                                    w_self, b_self, w_out, b_out, out);
}

// Round 4
// 119.779 us; speedup vs baseline: 1.6118x; 1.0497x over previous
//
// Round 15: fix k_zepi's 160-block grid (96/256 CUs idle during the VALU-bound
// epilogue = the measured ~70 us). Linearity-zbar (Qsum = xbar*Wq + 128*bq,
// computed race-free from x in K1) breaks the all-m locality constraint ->
// epilogue grid 1280 blocks (40 (b,e) x 4 nsl x 8 msl of 32n x 16m), 256 thr,
// 20 waves/CU fully co-resident, 5 blocks/CU exact balance.
// ws: proj [0, 1310720) + Qsum [1310720, +5120).
#include <hip/hip_runtime.h>
#include <hip/hip_bf16.h>

#define NB 8
#define NMAXN 128
#define PEH 64
#define NE 5
#define DSZ 64
#define NFEAT 8
#define TOTALN 1024         // NB*NMAXN
#define PCOLS 1280          // 4*E*PE
#define QSOFF 1310720       // Qsum: [be][pass][64] floats

// out layout (FLOAT32 offsets): e_hat, x_hat, edge_mask, mask
#define OUT_XHAT (NB*NMAXN*NMAXN*NE)              // 655360
#define OUT_EM   (OUT_XHAT + TOTALN*NFEAT)        // 663552
#define OUT_MASK (OUT_EM + NB*NMAXN*NMAXN)        // 794624

// ---------------- K1: proj GEMM (0..159) + misc (160..208) + Qsum (209..248), 256 thr
__global__ __launch_bounds__(256)
void k_front(const float* __restrict__ x,
             const float* __restrict__ w_attn, const float* __restrict__ b_attn,
             const float* __restrict__ w_node, const float* __restrict__ b_node,
             float* __restrict__ ws, float* __restrict__ out)
{
    int blk = blockIdx.x, t = threadIdx.x;
    if (blk < 160) {                       // ---------- proj GEMM
        __shared__ alignas(16) float xs[64 * 68];   // [k][row], pad 68
        int rt = blk / 10, ct = blk - 10 * rt;
        int r0 = rt * 64, c0 = ct * 128;
        #pragma unroll
        for (int it = 0; it < 4; it++) {
            int g = it * 256 + t;          // 0..1023
            int row = g >> 4, kk = (g & 15) * 4;
            float4 v = *(const float4*)&x[(r0 + row) * PEH + kk];
            xs[(kk + 0) * 68 + row] = v.x;
            xs[(kk + 1) * 68 + row] = v.y;
            xs[(kk + 2) * 68 + row] = v.z;
            xs[(kk + 3) * 68 + row] = v.w;
        }
        __syncthreads();
        int tx = t & 31, ty = t >> 5;
        int cc = c0 + 4 * tx, rr = 8 * ty;
        float4 bb = *(const float4*)&b_attn[cc];
        float acc[8][4];
        #pragma unroll
        for (int r = 0; r < 8; r++) {
            acc[r][0] = bb.x; acc[r][1] = bb.y; acc[r][2] = bb.z; acc[r][3] = bb.w;
        }
        const float* wp = w_attn + cc;
        #pragma unroll 8
        for (int k = 0; k < 64; k++) {
            float4 w4 = *(const float4*)&wp[k * PCOLS];
            float4 xa = *(const float4*)&xs[k * 68 + rr];
            float4 xb = *(const float4*)&xs[k * 68 + rr + 4];
            float xr[8] = {xa.x, xa.y, xa.z, xa.w, xb.x, xb.y, xb.z, xb.w};
            #pragma unroll
            for (int r = 0; r < 8; r++) {
                acc[r][0] = fmaf(xr[r], w4.x, acc[r][0]);
                acc[r][1] = fmaf(xr[r], w4.y, acc[r][1]);
                acc[r][2] = fmaf(xr[r], w4.z, acc[r][2]);
                acc[r][3] = fmaf(xr[r], w4.w, acc[r][3]);
            }
        }
        #pragma unroll
        for (int r = 0; r < 8; r++)
            *(float4*)&ws[(r0 + rr + r) * PCOLS + cc] =
                make_float4(acc[r][0], acc[r][1], acc[r][2], acc[r][3]);
        return;
    }
    if (blk >= 209) {                      // ---------- Qsum: one (b,e) per block
        __shared__ float xb4[4][64];
        __shared__ float xbar[64];
        int be = blk - 209;
        int b = be / 5, e = be - 5 * b;
        int d = t & 63, qq = t >> 6;
        float s = 0.f;
        #pragma unroll 8
        for (int r = qq * 32; r < qq * 32 + 32; r++)
            s += x[(b * NMAXN + r) * PEH + d];
        xb4[qq][d] = s;
        __syncthreads();
        if (t < 64) xbar[t] = xb4[0][t] + xb4[1][t] + xb4[2][t] + xb4[3][t];
        __syncthreads();
        if (t < 128) {
            int p = t >> 6;                // 0: q1 cols, 1: q2 cols
            int c = (p ? 960 : 320) + e * 64 + (t & 63);
            float acc = 128.0f * b_attn[c];
            #pragma unroll 8
            for (int dd = 0; dd < 64; dd++)
                acc = fmaf(xbar[dd], w_attn[dd * PCOLS + c], acc);
            ws[QSOFF + be * 128 + t] = acc;
        }
        return;
    }
    int b2 = blk - 160;
    if (b2 < 32) {                         // ---------- x_hat: 8192 outputs
        int g = b2 * 256 + t;
        int row = g >> 3, f = g & 7;
        const float* xr = x + row * PEH;
        float acc = b_node[f];
        #pragma unroll 8
        for (int k = 0; k < PEH; k++) acc = fmaf(xr[k], w_node[k * NFEAT + f], acc);
        out[OUT_XHAT + g] = acc;
    } else if (b2 < 48) {                  // ---------- edge_mask
        int base = (b2 - 32) * 8192;
        for (int g = base + t; g < base + 8192; g += 256) {
            int n = (g >> 7) & 127, m = g & 127;
            out[OUT_EM + g] = (n == m) ? 0.0f : 1.0f;
        }
    } else {                               // ---------- mask
        for (int g = t; g < 1024; g += 256) out[OUT_MASK + g] = 1.0f;
    }
}

// gelu tanh-approx: x * sigmoid(2u), u=sqrt(2/pi)(x+0.044715x^3)
__device__ __forceinline__ float gelu_fast(float x) {
    float x2 = x * x;
    float w  = -1.5957691216057308f * x * fmaf(0.044715f, x2, 1.0f);   // -2u
    float ew = __expf(w);
    return x * __builtin_amdgcn_rcpf(1.0f + ew);
}

// ---------------- K2: z + epilogue, fine grid. 1280 blocks = (b,e) x 4 nsl x 8 msl.
// Tile 32n x 16m, 256 thr, thread = (n = n0+ty, m = m0+2tx, m0+2tx+1).
// zbar[n] = sum_p sc_p*(k_p[n].Qsum_p) - z[n,n], computed by t<32 from staged smA.
__global__ __launch_bounds__(256)
void k_zepi(const float* __restrict__ ws, const float* __restrict__ qv,
            const float* __restrict__ w_phi, const float* __restrict__ b_phi,
            const float* __restrict__ w_ctx,
            const float* __restrict__ w_self, const float* __restrict__ b_self,
            const float* __restrict__ w_out, const float* __restrict__ b_out,
            float* __restrict__ out)
{
    __shared__ alignas(16) float smA[32 * 68];   // [n-local][k], scaled
    __shared__ alignas(16) float smQ[16 * 68];   // [m-local][k], unscaled
    __shared__ alignas(16) float4 cwi[64];       // (w_self, wpc, c1, w_out)
    __shared__ alignas(16) float qs[64];         // Qsum for current pass
    __shared__ float zbs[32];

    int t = threadIdx.x, blk = blockIdx.x;
    int be = blk >> 5, r5 = blk & 31;
    int nsl = r5 >> 3, msl = r5 & 7;
    int b = be / 5, e = be - 5 * b;
    int n0 = nsl * 32, m0 = msl * 16;

    // per-block consts (t<64): cwi = (w_self, w_phi.w_ctx, b_self + b_phi.w_ctx, w_out)
    if (t < 64) {
        float wpv = 0.f, bpv = 0.f;
        #pragma unroll 8
        for (int i = 0; i < 64; i++) {
            float wc = w_ctx[i * 64 + t];
            wpv = fmaf(w_phi[i], wc, wpv);
            bpv = fmaf(b_phi[i], wc, bpv);
        }
        cwi[t] = make_float4(w_self[t], wpv, b_self[t] + bpv, w_out[t]);
    }
    float ang = 6.2831853071795864f * qv[b];
    float fac = (2.0f - cosf(ang)) / sinf(ang);
    const float scale = 0.05590169943749474f;   // 1/sqrt(320)

    int ty = t >> 3;           // n-local 0..31
    int tx = t & 7;            // m-group (2 m's)
    float acc0 = 0.f, acc1 = 0.f;
    float zacc = 0.f;          // t<32: zbar accumulator

    #pragma unroll
    for (int pass = 0; pass < 2; pass++) {
        __syncthreads();                        // prior-pass smA/smQ/qs reads done
        int cK = (pass ? 640 : 0)   + e * 64;
        int cQ = (pass ? 960 : 320) + e * 64;
        float sc = pass ? (scale * fac) : scale;
        {   // stage smA: 32 n-rows x 64 k (scaled)
            int r = t >> 3, kk = (t & 7) * 8;
            const float* pr = &ws[(b * NMAXN + n0 + r) * PCOLS + cK + kk];
            float4 v0 = *(const float4*)&pr[0];
            float4 v1 = *(const float4*)&pr[4];
            *(float4*)&smA[r * 68 + kk]     = make_float4(sc*v0.x, sc*v0.y, sc*v0.z, sc*v0.w);
            *(float4*)&smA[r * 68 + kk + 4] = make_float4(sc*v1.x, sc*v1.y, sc*v1.z, sc*v1.w);
        }
        {   // stage smQ: 16 m-rows x 64 k (unscaled)
            int r = t >> 4, kk = (t & 15) * 4;
            float4 v = *(const float4*)&ws[(b * NMAXN + m0 + r) * PCOLS + cQ + kk];
            *(float4*)&smQ[r * 68 + kk] = v;
        }
        if (t < 64) qs[t] = ws[QSOFF + be * 128 + pass * 64 + t];
        __syncthreads();
        // z: acc += k_scaled[n] . q[m]
        const float* ar = &smA[ty * 68];
        const float* qa = &smQ[(2 * tx) * 68];
        const float* qb = &smQ[(2 * tx + 1) * 68];
        #pragma unroll 4
        for (int i = 0; i < 16; i++) {
            float4 a4 = *(const float4*)&ar[4 * i];
            float4 u4 = *(const float4*)&qa[4 * i];
            float4 v4 = *(const float4*)&qb[4 * i];
            acc0 = fmaf(a4.x, u4.x, acc0); acc0 = fmaf(a4.y, u4.y, acc0);
            acc0 = fmaf(a4.z, u4.z, acc0); acc0 = fmaf(a4.w, u4.w, acc0);
            acc1 = fmaf(a4.x, v4.x, acc1); acc1 = fmaf(a4.y, v4.y, acc1);
            acc1 = fmaf(a4.z, v4.z, acc1); acc1 = fmaf(a4.w, v4.w, acc1);
        }
        // zbar partial for this pass: t<32 handles n-local t
        if (t < 32) {
            const float* arow = &smA[t * 68];
            const float* qdg  = &ws[(b * NMAXN + n0 + t) * PCOLS + cQ];
            float dq = 0.f, dg = 0.f;
            #pragma unroll 4
            for (int i = 0; i < 16; i++) {
                float4 a4 = *(const float4*)&arow[4 * i];
                float4 s4 = *(const float4*)&qs[4 * i];
                float4 d4 = *(const float4*)&qdg[4 * i];
                dq = fmaf(a4.x, s4.x, dq); dq = fmaf(a4.y, s4.y, dq);
                dq = fmaf(a4.z, s4.z, dq); dq = fmaf(a4.w, s4.w, dq);
                dg = fmaf(a4.x, d4.x, dg); dg = fmaf(a4.y, d4.y, dg);
                dg = fmaf(a4.z, d4.z, dg); dg = fmaf(a4.w, d4.w, dg);
            }
            zacc += dq - dg;
        }
    }
    __syncthreads();
    if (t < 32) zbs[t] = zacc * (1.0f / 127.0f);
    __syncthreads();
    float zbv = zbs[ty];

    // epilogue: 2 gelu chains over d=0..63
    float bo = b_out[0];
    float o0 = bo, o1 = bo;
    #pragma unroll 8
    for (int d = 0; d < 64; d++) {
        float4 c = cwi[d];
        float zc = fmaf(zbv, c.y, c.z);
        o0 = fmaf(gelu_fast(fmaf(acc0, c.x, zc)), c.w, o0);
        o1 = fmaf(gelu_fast(fmaf(acc1, c.x, zc)), c.w, o1);
    }
    // e_hat[b, m, n, e]
    int n = n0 + ty, m = m0 + 2 * tx;
    out[(b * NMAXN + m) * 640 + n * 5 + e]       = o0;
    out[(b * NMAXN + m + 1) * 640 + n * 5 + e]   = o1;
}

extern "C" void kernel_launch(void* const* d_in, const int* in_sizes, int n_in,
                              void* d_out, int out_size, void* d_ws, size_t ws_size,
                              hipStream_t stream)
{
    const float* x      = (const float*)d_in[0];
    // d_in[1] = batch (int32) — full sorted graphs, unused
    const float* q      = (const float*)d_in[2];
    const float* w_attn = (const float*)d_in[3];
    const float* b_attn = (const float*)d_in[4];
    const float* w_node = (const float*)d_in[5];
    const float* b_node = (const float*)d_in[6];
    const float* w_phi  = (const float*)d_in[7];
    const float* b_phi  = (const float*)d_in[8];
    const float* w_ctx  = (const float*)d_in[9];
    const float* w_self = (const float*)d_in[10];
    const float* b_self = (const float*)d_in[11];
    const float* w_out  = (const float*)d_in[12];
    const float* b_out  = (const float*)d_in[13];
    float* ws  = (float*)d_ws;
    float* out = (float*)d_out;

    k_front<<<249, 256, 0, stream>>>(x, w_attn, b_attn, w_node, b_node, ws, out);
    k_zepi<<<1280, 256, 0, stream>>>(ws, q, w_phi, b_phi, w_ctx,
                                     w_self, b_self, w_out, b_out, out);
}